// Round 7
// baseline (171.130 us; speedup 1.0000x reference)
//
#include <hip/hip_runtime.h>
#include <hip/hip_bf16.h>
#include <math.h>

#define NROWS   16384
#define IN_DIM  64
#define HID     256
#define OUT_DIM 64
#define NEXP    256
#define MT      112    // row slots per block (cnt ~ 64+-8)
#define HP      264    // padded LDS row stride in bf16 elems (528 B)

typedef __attribute__((ext_vector_type(8))) short short8;   // 8 bf16 (4 VGPRs)
typedef __attribute__((ext_vector_type(4))) float f32x4;
typedef __attribute__((ext_vector_type(4))) unsigned uint4v;
typedef __attribute__((ext_vector_type(2))) unsigned uint2v;

// ---------------- fused bucketing kernel (single block) ----------------

__global__ __launch_bounds__(1024) void prep_k(const int* __restrict__ ind,
                                               int* __restrict__ rows,
                                               int* __restrict__ offsets) {
  __shared__ int hist[NEXP];
  __shared__ int scan[NEXP];
  __shared__ int cur[NEXP];
  int t = threadIdx.x;
  if (t < NEXP) hist[t] = 0;
  __syncthreads();
  for (int n = t; n < NROWS; n += 1024) atomicAdd(&hist[ind[n]], 1);
  __syncthreads();
  if (t < NEXP) scan[t] = hist[t];
  __syncthreads();
  for (int d = 1; d < NEXP; d <<= 1) {
    int v = (t < NEXP && t >= d) ? scan[t - d] : 0;
    __syncthreads();
    if (t < NEXP) scan[t] += v;
    __syncthreads();
  }
  if (t < NEXP) {
    int exc = scan[t] - hist[t];
    offsets[t] = exc;
    cur[t] = exc;
    if (t == NEXP - 1) offsets[NEXP] = scan[t];
  }
  __syncthreads();
  for (int n = t; n < NROWS; n += 1024) {
    int p = atomicAdd(&cur[ind[n]], 1);
    rows[p] = n;
  }
}

// ---------------- helpers ----------------

// Truncating fp32->bf16 pair pack: ONE v_perm_b32. Weights only (<=1 ulp).
__device__ __forceinline__ unsigned pk2_trunc(float a, float b) {
  return __builtin_amdgcn_perm(__builtin_bit_cast(unsigned, b),
                               __builtin_bit_cast(unsigned, a), 0x07060302u);
}

// RNE pack (activations) — HW packed convert.
__device__ __forceinline__ unsigned pk2_rn(float a, float b) {
  __hip_bfloat162 h = __float22bfloat162_rn(float2{a, b});
  unsigned r;
  __builtin_memcpy(&r, &h, 4);
  return r;
}

__device__ __forceinline__ short8 cvt8w(f32x4 w0, f32x4 w1) {
  uint4v u;
  u.x = pk2_trunc(w0.x, w0.y);
  u.y = pk2_trunc(w0.z, w0.w);
  u.z = pk2_trunc(w1.x, w1.y);
  u.w = pk2_trunc(w1.z, w1.w);
  return __builtin_bit_cast(short8, u);
}

__device__ __forceinline__ float fast_tanh(float v) {
  float e = __expf(2.f * v);
  return 1.f - 2.f * __builtin_amdgcn_rcpf(e + 1.f);
}

// Issue a whole layer-slab of weight loads (KS k-steps, 2x f32x4 each).
template <int KS>
__device__ __forceinline__ void wload(f32x4 (&wb)[KS][2], const float* __restrict__ wr) {
#pragma unroll
  for (int ks = 0; ks < KS; ks++) {
    wb[ks][0] = *(const f32x4*)(wr + ks * 32);
    wb[ks][1] = *(const f32x4*)(wr + ks * 32 + 4);
  }
}

// MFMA sweep with preloaded weights. Hin: [MT][HP] bf16 activations.
template <int K, int NNT>
__device__ __forceinline__ void layer_mfma(const f32x4 (&wb)[K / 32][2], f32x4 bv,
                                           const unsigned short* __restrict__ Hin,
                                           int l15, int q, f32x4 (&acc)[NNT]) {
  constexpr int KS = K / 32;
#pragma unroll
  for (int nt = 0; nt < NNT; nt++) acc[nt] = bv;
#pragma unroll
  for (int ks = 0; ks < KS; ks++) {
    short8 a = cvt8w(wb[ks][0], wb[ks][1]);
#pragma unroll
    for (int nt = 0; nt < NNT; nt++) {
      short8 b = *(const short8*)&Hin[(nt * 16 + l15) * HP + ks * 32 + q * 8];
      acc[nt] = __builtin_amdgcn_mfma_f32_16x16x32_bf16(a, b, acc[nt], 0, 0, 0);
    }
  }
}

// tanh + RNE pack + store h-frags at neuron-col base `col`.
template <int NNT>
__device__ __forceinline__ void write_h1(f32x4 (&acc)[NNT], unsigned short* H,
                                         int col, int l15) {
#pragma unroll
  for (int nt = 0; nt < NNT; nt++) {
    uint2v v;
    v.x = pk2_rn(fast_tanh(acc[nt].x), fast_tanh(acc[nt].y));
    v.y = pk2_rn(fast_tanh(acc[nt].z), fast_tanh(acc[nt].w));
    *(uint2v*)&H[(nt * 16 + l15) * HP + col] = v;
  }
}

// ---------------- per-tile body, templated on active row-tile count ----------

template <int NNT>
__device__ __forceinline__ void tile_body(
    const float* __restrict__ W1e, const float* __restrict__ W2e,
    const float* __restrict__ Wle,
    f32x4 b1v, f32x4 b2v, f32x4 blv,
    unsigned short* __restrict__ H, int l15, int q, int w,
    int m3, int ntA,
    const int* __restrict__ rows, int beg, int cnt, int mt0,
    const float* __restrict__ x, float* __restrict__ out, int sm, int sc) {
  // Issue layer-1 AND layer-2 weight streams up front; the first barrier's
  // vmcnt drain overlaps both with the x staging loads (one latency hit).
  f32x4 w1b[2][2], w2b[8][2];
  wload<2>(w1b, W1e);
  wload<8>(w2b, W2e);

  // ---- stage x tile (fp32 global -> bf16 LDS cols 0..63), zero-pad tail
  if (sm < MT) {
    int gm = mt0 + sm;
    bool val = gm < cnt;
    int r = val ? rows[beg + gm] : 0;
    const float* xr = x + (size_t)r * IN_DIM + sc;
    uint4v u;
    if (val) {
      f32x4 a0 = *(const f32x4*)(xr);
      f32x4 a1 = *(const f32x4*)(xr + 4);
      u.x = pk2_rn(a0.x, a0.y); u.y = pk2_rn(a0.z, a0.w);
      u.z = pk2_rn(a1.x, a1.y); u.w = pk2_rn(a1.z, a1.w);
    } else {
      u = (uint4v){0, 0, 0, 0};
    }
    *(uint4v*)&H[sm * HP + sc] = u;
  }
  __syncthreads();

  // ---- layer1: x(K=64) -> h1 (wave's 16 neurons), tanh
  f32x4 acc[NNT];
  layer_mfma<IN_DIM, NNT>(w1b, b1v, H, l15, q, acc);
  __syncthreads();  // all x reads done before h1 writes clobber H
  write_h1<NNT>(acc, H, w * 16 + q * 4, l15);
  __syncthreads();

  // ---- layer2: h1(K=256) -> h2, tanh (in place)
  layer_mfma<HID, NNT>(w2b, b2v, H, l15, q, acc);
  // issue layer-3 weight stream now; latency hides under tanh + barrier
  f32x4 wlb[8][2];
  wload<8>(wlb, Wle);
  __syncthreads();  // all h1 reads done before h2 writes
  write_h1<NNT>(acc, H, w * 16 + q * 4, l15);
  __syncthreads();

  // ---- layer3: h2(K=256) -> out; wave: neuron-tile m3, row-tiles ntA, ntA+4
  {
    const int ntB = (ntA + 4 < NNT) ? ntA + 4 : 0;  // clamped; store guarded
    f32x4 a3[2];
    a3[0] = blv; a3[1] = blv;
#pragma unroll
    for (int ks = 0; ks < 8; ks++) {
      short8 a = cvt8w(wlb[ks][0], wlb[ks][1]);
      short8 bA = *(const short8*)&H[(ntA * 16 + l15) * HP + ks * 32 + q * 8];
      short8 bB = *(const short8*)&H[(ntB * 16 + l15) * HP + ks * 32 + q * 8];
      a3[0] = __builtin_amdgcn_mfma_f32_16x16x32_bf16(a, bA, a3[0], 0, 0, 0);
      a3[1] = __builtin_amdgcn_mfma_f32_16x16x32_bf16(a, bB, a3[1], 0, 0, 0);
    }
    {
      int gm = mt0 + ntA * 16 + l15;
      if (gm < cnt) {
        int r = rows[beg + gm];
        *(f32x4*)(out + (size_t)r * OUT_DIM + m3 * 16 + q * 4) = a3[0];
      }
    }
    if (ntA + 4 < NNT) {
      int gm = mt0 + (ntA + 4) * 16 + l15;
      if (gm < cnt) {
        int r = rows[beg + gm];
        *(f32x4*)(out + (size_t)r * OUT_DIM + m3 * 16 + q * 4) = a3[1];
      }
    }
  }
}

// ---------------- main MLP kernel ----------------
// One block per expert; 1024 threads = 16 waves (4/SIMD).
// Layers 1/2: wave w owns neurons w*16..+15. Layer 3: wave w owns neuron-tile
// (w&3), row-tiles (w>>2) and (w>>2)+4.

__global__ __launch_bounds__(1024, 4) void mlp_k(
    const float* __restrict__ x,
    const float* __restrict__ W1, const float* __restrict__ b1,
    const float* __restrict__ W2, const float* __restrict__ b2,
    const float* __restrict__ Wl, const float* __restrict__ bl,
    const int* __restrict__ rows, const int* __restrict__ offsets,
    float* __restrict__ out) {
  __shared__ __align__(16) unsigned short H[MT * HP];  // 59136 B

  const int t = threadIdx.x;
  const int w = t >> 6;
  const int l15 = t & 15;
  const int q = (t >> 4) & 3;
  const int e = blockIdx.x;
  const int beg = offsets[e];
  const int cnt = offsets[e + 1] - beg;

  const float* W1e = W1 + (size_t)e * HID * IN_DIM + (size_t)(w * 16 + l15) * IN_DIM + q * 8;
  const float* W2e = W2 + (size_t)e * HID * HID + (size_t)(w * 16 + l15) * HID + q * 8;
  const int m3 = w & 3;
  const int ntA = w >> 2;
  const float* Wle = Wl + (size_t)e * OUT_DIM * HID + (size_t)(m3 * 16 + l15) * HID + q * 8;
  const f32x4 b1v = *(const f32x4*)(b1 + e * HID + w * 16 + q * 4);
  const f32x4 b2v = *(const f32x4*)(b2 + e * HID + w * 16 + q * 4);
  const f32x4 blv = *(const f32x4*)(bl + e * OUT_DIM + m3 * 16 + q * 4);

  const int sm = t >> 3;
  const int sc = (t & 7) * 8;

  for (int mt0 = 0; mt0 < cnt; mt0 += MT) {
    if (mt0) __syncthreads();  // H reuse across (rare) extra tiles
    int rem = cnt - mt0;
    if (rem > MT) rem = MT;
    int ntiles = (rem + 15) >> 4;  // 1..7 active row-tiles
    if (ntiles <= 4)
      tile_body<4>(W1e, W2e, Wle, b1v, b2v, blv, H, l15, q, w, m3, ntA,
                   rows, beg, cnt, mt0, x, out, sm, sc);
    else if (ntiles == 5)
      tile_body<5>(W1e, W2e, Wle, b1v, b2v, blv, H, l15, q, w, m3, ntA,
                   rows, beg, cnt, mt0, x, out, sm, sc);
    else if (ntiles == 6)
      tile_body<6>(W1e, W2e, Wle, b1v, b2v, blv, H, l15, q, w, m3, ntA,
                   rows, beg, cnt, mt0, x, out, sm, sc);
    else
      tile_body<7>(W1e, W2e, Wle, b1v, b2v, blv, H, l15, q, w, m3, ntA,
                   rows, beg, cnt, mt0, x, out, sm, sc);
  }
}

// ---------------- launcher ----------------

extern "C" void kernel_launch(void* const* d_in, const int* in_sizes, int n_in,
                              void* d_out, int out_size, void* d_ws, size_t ws_size,
                              hipStream_t stream) {
  const float* x   = (const float*)d_in[0];
  const int*   ind = (const int*)d_in[1];
  const float* W1  = (const float*)d_in[2];
  const float* b1  = (const float*)d_in[3];
  const float* W2  = (const float*)d_in[4];
  const float* b2  = (const float*)d_in[5];
  const float* Wl  = (const float*)d_in[6];
  const float* bl  = (const float*)d_in[7];
  float* out = (float*)d_out;

  int* offsets = (int*)d_ws;        // 257 ints
  int* rows    = (int*)d_ws + 260;  // 16384 ints

  prep_k<<<1, 1024, 0, stream>>>(ind, rows, offsets);
  mlp_k<<<NEXP, 1024, 0, stream>>>(x, W1, b1, W2, b2, Wl, bl, rows, offsets, out);
}